// Round 10
// baseline (77.326 us; speedup 1.0000x reference)
//
#include <hip/hip_runtime.h>

#define NV 100000
#define NJ 24
#define NP 207
#define NPART 25
#define NWAVES 4096            // k_stream: 1024 blocks * 4 waves

// ---------------------------------------------------------------------------
// K1: v_shaped = v_template + shapedirs @ betas, flat over 300000 rows of 10.
// ---------------------------------------------------------------------------
__global__ __launch_bounds__(256) void k_shape(
    const float* __restrict__ betas, const float* __restrict__ v_template,
    const float* __restrict__ shapedirs, float* __restrict__ v_shaped) {
  __shared__ float sb[10];
  if (threadIdx.x < 10) sb[threadIdx.x] = betas[threadIdx.x];
  __syncthreads();
  int R = blockIdx.x * 256 + threadIdx.x;
  if (R >= 3 * NV) return;
  const float2* sd = (const float2*)(shapedirs + (size_t)R * 10);
  float a = v_template[R];
  #pragma unroll
  for (int s = 0; s < 5; ++s) {
    float2 x = sd[s];
    a += x.x * sb[2 * s] + x.y * sb[2 * s + 1];
  }
  v_shaped[R] = a;
}

// ---------------------------------------------------------------------------
// K2: J partials.  grid = (24 joints, 25 parts), pure float4 loads.
// ---------------------------------------------------------------------------
__global__ __launch_bounds__(256) void k_jreg(
    const float* __restrict__ Jreg, const float* __restrict__ v_shaped,
    float* __restrict__ jpart) {
  int j = blockIdx.x, part = blockIdx.y, tid = threadIdx.x;
  const int SL = NV / NPART;  // 4000
  int v0 = part * SL;
  const float4* w4 = (const float4*)(Jreg + (size_t)j * NV + v0);
  const float4* s4 = (const float4*)(v_shaped + (size_t)3 * v0);
  float s0 = 0.f, s1 = 0.f, s2 = 0.f;
  for (int i4 = tid; i4 < SL / 4; i4 += 256) {
    float4 w = w4[i4];
    float4 A = s4[3 * i4 + 0];
    float4 B = s4[3 * i4 + 1];
    float4 C = s4[3 * i4 + 2];
    s0 += w.x * A.x + w.y * A.w + w.z * B.z + w.w * C.y;
    s1 += w.x * A.y + w.y * B.x + w.z * B.w + w.w * C.z;
    s2 += w.x * A.z + w.y * B.y + w.z * C.x + w.w * C.w;
  }
  __shared__ float red[256][3];
  red[tid][0] = s0; red[tid][1] = s1; red[tid][2] = s2;
  __syncthreads();
  for (int off = 128; off > 0; off >>= 1) {
    if (tid < off) {
      red[tid][0] += red[tid + off][0];
      red[tid][1] += red[tid + off][1];
      red[tid][2] += red[tid + off][2];
    }
    __syncthreads();
  }
  if (tid < 3) jpart[(part * NJ + j) * 3 + tid] = red[0][tid];
}

// ---------------------------------------------------------------------------
// K3: single block: finalize J, rodrigues, FK chain, rel matrices, lrotmin
// ---------------------------------------------------------------------------
__global__ __launch_bounds__(64) void k_fk(
    const float* __restrict__ pose, const float* __restrict__ jpart,
    float* __restrict__ lrot, float* __restrict__ rel) {
  __shared__ float J[NJ][3];
  __shared__ float R[NJ][9];
  __shared__ float G[NJ][12];
  int tid = threadIdx.x;
  if (tid < NJ) {
    for (int k = 0; k < 3; ++k) {
      float a = 0.f;
      for (int part = 0; part < NPART; ++part) a += jpart[(part * NJ + tid) * 3 + k];
      J[tid][k] = a;
    }
    float rx = pose[tid * 3 + 0], ry = pose[tid * 3 + 1], rz = pose[tid * 3 + 2];
    float tx = rx + 1e-8f, ty = ry + 1e-8f, tz = rz + 1e-8f;
    float theta = sqrtf(tx * tx + ty * ty + tz * tz);
    float x = rx / theta, y = ry / theta, z = rz / theta;
    float c = cosf(theta), s = sinf(theta), C = 1.f - c;
    float* Rr = R[tid];
    Rr[0] = c + C * x * x;     Rr[1] = C * x * y - s * z; Rr[2] = C * x * z + s * y;
    Rr[3] = C * x * y + s * z; Rr[4] = c + C * y * y;     Rr[5] = C * y * z - s * x;
    Rr[6] = C * x * z - s * y; Rr[7] = C * y * z + s * x; Rr[8] = c + C * z * z;
    if (tid >= 1) {
      #pragma unroll
      for (int e = 0; e < 9; ++e) {
        float id = (e == 0 || e == 4 || e == 8) ? 1.f : 0.f;
        lrot[(tid - 1) * 9 + e] = Rr[e] - id;
      }
    }
  }
  __syncthreads();
  if (tid == 0) {
    const int par[NJ] = {-1,0,0,0,1,2,3,4,5,6,7,8,9,9,9,12,13,14,16,17,18,19,20,21};
    for (int a = 0; a < 3; ++a) {
      for (int b = 0; b < 3; ++b) G[0][a * 4 + b] = R[0][a * 3 + b];
      G[0][a * 4 + 3] = J[0][a];
    }
    for (int i = 1; i < NJ; ++i) {
      int p = par[i];
      float t0 = J[i][0] - J[p][0], t1 = J[i][1] - J[p][1], t2 = J[i][2] - J[p][2];
      for (int a = 0; a < 3; ++a) {
        float g0 = G[p][a * 4 + 0], g1 = G[p][a * 4 + 1], g2 = G[p][a * 4 + 2];
        for (int b = 0; b < 3; ++b)
          G[i][a * 4 + b] = g0 * R[i][0 * 3 + b] + g1 * R[i][1 * 3 + b] + g2 * R[i][2 * 3 + b];
        G[i][a * 4 + 3] = G[p][a * 4 + 3] + g0 * t0 + g1 * t1 + g2 * t2;
      }
    }
  }
  __syncthreads();
  if (tid < NJ) {
    for (int a = 0; a < 3; ++a) {
      float corr = G[tid][a * 4 + 0] * J[tid][0] + G[tid][a * 4 + 1] * J[tid][1] +
                   G[tid][a * 4 + 2] * J[tid][2];
      rel[tid * 12 + a * 4 + 0] = G[tid][a * 4 + 0];
      rel[tid * 12 + a * 4 + 1] = G[tid][a * 4 + 1];
      rel[tid * 12 + a * 4 + 2] = G[tid][a * 4 + 2];
      rel[tid * 12 + a * 4 + 3] = G[tid][a * 4 + 3] - corr;
    }
  }
}

// ---------------------------------------------------------------------------
// K4: pure-streaming pose-blend + LBS. One WAVE per vertex, grid-stride
// (step 4096 == 0 mod 4, so phase s = v&3 is wave-constant). Row window
// starts at 621*v - s (16B aligned); the phase shift is folded into 36
// REGISTER weights per lane (zeroed outside the row / inactive lanes), so
// there is no LDS tile, no barrier, no DMA queue: 3 aligned float4 loads
// per vertex (1KB/instr), dot in regs, 64-lane shfl_xor reduce, in-lane LBS.
// ---------------------------------------------------------------------------
__global__ __launch_bounds__(256) void k_stream(
    const float* __restrict__ posedirs, const float* __restrict__ wgt,
    const float* __restrict__ lrot, const float* __restrict__ rel,
    const float* __restrict__ scale, const float* __restrict__ trans,
    float* __restrict__ vbuf) {
  __shared__ float lrs[NP];
  int tid = threadIdx.x;
  if (tid < NP) lrs[tid] = lrot[tid];
  __syncthreads();

  int lane = tid & 63;
  int wid0 = blockIdx.x * 4 + (tid >> 6);  // 0..4095
  int s = wid0 & 3;                        // phase, constant per wave

  // per-lane register weights: w{k}[r].{c} = lrotmin[p] if element
  // e = 4*(lane+64r)+c-s lies in segment k of the 621-float row, else 0.
  float4 w0[3], w1[3], w2[3];
  #pragma unroll
  for (int r = 0; r < 3; ++r) {
    float t0[4], t1[4], t2[4];
    #pragma unroll
    for (int c = 0; c < 4; ++c) {
      int m = 4 * (lane + 64 * r) + c;
      int e = m - s;
      bool act = (r < 2 || lane < 28) && (e >= 0) && (e < 3 * NP);
      float v0 = 0.f, v1 = 0.f, v2 = 0.f;
      if (act) {
        int k = e / NP;
        int p = e - NP * k;
        float val = lrs[p];
        v0 = (k == 0) ? val : 0.f;
        v1 = (k == 1) ? val : 0.f;
        v2 = (k == 2) ? val : 0.f;
      }
      t0[c] = v0; t1[c] = v1; t2[c] = v2;
    }
    w0[r] = make_float4(t0[0], t0[1], t0[2], t0[3]);
    w1[r] = make_float4(t1[0], t1[1], t1[2], t1[3]);
    w2[r] = make_float4(t2[0], t2[1], t2[2], t2[3]);
  }

  // per-lane LBS constants (zero-filled on inactive lanes)
  float rlq[12];
  #pragma unroll
  for (int e = 0; e < 12; ++e) rlq[e] = (lane < NJ) ? rel[lane * 12 + e] : 0.f;
  float sc = scale[0];
  float tr = (lane < 3) ? trans[lane] : 0.f;

  for (int v = wid0; v < NV; v += NWAVES) {
    const float4* src4 = (const float4*)(posedirs + (size_t)(3 * NP) * v - s);
    float4 x0 = src4[lane];
    float4 x1 = src4[64 + lane];
    float4 x2 = (lane < 28) ? src4[128 + lane] : make_float4(0.f, 0.f, 0.f, 0.f);
    float pvl = (lane < 3) ? vbuf[(size_t)3 * v + lane] : 0.f;
    float wj  = (lane < NJ) ? wgt[(size_t)NJ * v + lane] : 0.f;

    float a0 = x0.x * w0[0].x + x0.y * w0[0].y + x0.z * w0[0].z + x0.w * w0[0].w
             + x1.x * w0[1].x + x1.y * w0[1].y + x1.z * w0[1].z + x1.w * w0[1].w
             + x2.x * w0[2].x + x2.y * w0[2].y + x2.z * w0[2].z + x2.w * w0[2].w;
    float a1 = x0.x * w1[0].x + x0.y * w1[0].y + x0.z * w1[0].z + x0.w * w1[0].w
             + x1.x * w1[1].x + x1.y * w1[1].y + x1.z * w1[1].z + x1.w * w1[1].w
             + x2.x * w1[2].x + x2.y * w1[2].y + x2.z * w1[2].z + x2.w * w1[2].w;
    float a2 = x0.x * w2[0].x + x0.y * w2[0].y + x0.z * w2[0].z + x0.w * w2[0].w
             + x1.x * w2[1].x + x1.y * w2[1].y + x1.z * w2[1].z + x1.w * w2[1].w
             + x2.x * w2[2].x + x2.y * w2[2].y + x2.z * w2[2].z + x2.w * w2[2].w;
    #pragma unroll
    for (int off = 32; off > 0; off >>= 1) {
      a0 += __shfl_xor(a0, off);
      a1 += __shfl_xor(a1, off);
      a2 += __shfl_xor(a2, off);
    }
    float p0 = __shfl(pvl, 0) + a0;
    float p1 = __shfl(pvl, 1) + a1;
    float p2 = __shfl(pvl, 2) + a2;
    float q0 = rlq[0] * p0 + rlq[1] * p1 + rlq[2]  * p2 + rlq[3];
    float q1 = rlq[4] * p0 + rlq[5] * p1 + rlq[6]  * p2 + rlq[7];
    float q2 = rlq[8] * p0 + rlq[9] * p1 + rlq[10] * p2 + rlq[11];
    float r0 = wj * q0, r1 = wj * q1, r2 = wj * q2;
    #pragma unroll
    for (int off = 32; off > 0; off >>= 1) {
      r0 += __shfl_xor(r0, off);
      r1 += __shfl_xor(r1, off);
      r2 += __shfl_xor(r2, off);
    }
    if (lane < 3) {
      float oo = (lane == 0) ? r0 : (lane == 1) ? r1 : r2;
      vbuf[(size_t)3 * v + lane] = oo * sc + tr;
    }
  }
}

extern "C" void kernel_launch(void* const* d_in, const int* in_sizes, int n_in,
                              void* d_out, int out_size, void* d_ws, size_t ws_size,
                              hipStream_t stream) {
  const float* betas      = (const float*)d_in[0];
  const float* pose       = (const float*)d_in[1];
  const float* scale      = (const float*)d_in[2];
  const float* trans      = (const float*)d_in[3];
  const float* v_template = (const float*)d_in[4];
  const float* shapedirs  = (const float*)d_in[5];
  const float* posedirs   = (const float*)d_in[6];
  const float* Jreg       = (const float*)d_in[7];
  const float* weights    = (const float*)d_in[8];
  float* out = (float*)d_out;
  float* ws  = (float*)d_ws;

  float* jpart = ws;          // 25*24*3 = 1800 floats
  float* lrot  = ws + 1800;   // 207 floats
  float* rel   = ws + 2048;   // 288 floats

  k_shape<<<(3 * NV + 255) / 256, 256, 0, stream>>>(betas, v_template, shapedirs, out);
  k_jreg<<<dim3(NJ, NPART), 256, 0, stream>>>(Jreg, out, jpart);
  k_fk<<<1, 64, 0, stream>>>(pose, jpart, lrot, rel);
  k_stream<<<NWAVES / 4, 256, 0, stream>>>(posedirs, weights, lrot, rel, scale, trans, out);
}